// Round 7
// baseline (166.055 us; speedup 1.0000x reference)
//
#include <hip/hip_runtime.h>
#include <hip/hip_fp16.h>
#include <hip/hip_cooperative_groups.h>

namespace cg = cooperative_groups;

// Problem: Topo_60653528154131
//   x:[256,3,256,25] f32, centres:[64,2] f32, sharpness:[64,2] f32 -> out:[64] f32
//
// SINGLE cooperative kernel (256 blocks x 1024 threads, 1 block/CU), 3 grid syncs:
//   P1: block n: mean_{c,t} x[n] -> m[n,:] (global); INF-init its slice of Mp
//   P2: block i: stage m -> LDS, feat (all nodes, redundant), D2 row i in REGISTERS,
//       row-min edge key -> rk[i] (global); block 0: feat min/max -> LDS (persists)
//   P3: block b: deterministic Boruvka round-1 hooking from rk (ballot-rank renumber
//       -> identical cmap in every block), fold register-resident D2 row b into
//       Mp[ca][cb] via global atomicMin (storm distributed over 256 CUs)
//   P4: block 0 only: re-hook round 1 (records deaths), load Mp (n<=128) to LDS,
//       Boruvka rounds 2+ on shrinking matrices, deaths=sqrt(D2)/(max-min),
//       structure-element layer -> out[64]
//
// ws: m[6400]f32 @0, rk[256]u32 @25600, Mp[128*132]u32 @26624   (D16 eliminated)

#define WS_M   0
#define WS_RK  25600
#define WS_MP  26624

#define INF32 0xFFFFFFFFu
#define MPSTR 132
#define SA 132   // u32 stride, buffer A (cap 128 rows)
#define SB 68    // u32 stride, buffer B (cap 64 rows)
#define OFF_B (128 * SA)
// LDS overlay pool: P2 uses [0,51200) mS+featS; P3/P4 use [0,2048) maps,
// [4096, 4096+84992) Mb ping-pong, [89088, 93184) outpart.
#define POOL_BYTES 93184

// wave64 min-reduce step via DPP: invalid lanes keep old=INF
template <int CTRL>
__device__ __forceinline__ unsigned int dpp_min_step(unsigned int v) {
    unsigned int t = (unsigned int)__builtin_amdgcn_update_dpp(
        (int)0xFFFFFFFF, (int)v, CTRL, 0xF, 0xF, false);
    return (t < v) ? t : v;
}

// ---------------- wave0 Boruvka phase (DETERMINISTIC) ----------------
// hook -> 2-cycle break (optional death record) -> async pointer jump ->
// ballot-rank renumber (deterministic: identical result in every block).
// Wave-0 lanes only; no __syncthreads inside.
template <bool RECORD>
__device__ __forceinline__ void wave0_phase(int n, int lane,
        unsigned int* rowKeyS, unsigned char* parentS, unsigned char* newidS,
        unsigned char* cmapS, float* deaths, unsigned int* ncS, unsigned int* dcS) {
    unsigned int par[4];
    #pragma unroll
    for (int s = 0; s < 4; ++s) {         // hook
        const int i = lane + 64 * s;
        if (i < n) {
            const unsigned int rk = rowKeyS[i];
            const unsigned int u = (rk >> 8) & 0xFFu, v = rk & 0xFFu;
            unsigned int p = (u == (unsigned int)i) ? v : u;
            if (rk == INF32) p = (unsigned int)i;  // safety; complete graph: unused
            par[s] = p;
            parentS[i] = (unsigned char)p;
        }
    }
    #pragma unroll
    for (int s = 0; s < 4; ++s) {         // break mutual 2-cycles
        const int i = lane + 64 * s;
        if (i < n) {
            const unsigned int p = par[s];
            if (p != (unsigned int)i) {
                if (parentS[p] == (unsigned char)i && (unsigned int)i < p) {
                    parentS[i] = (unsigned char)i;   // winner stays root, no death
                } else if (RECORD) {
                    const unsigned int d = atomicAdd(dcS, 1u);
                    const unsigned int rk = rowKeyS[i];
                    deaths[d] = sqrtf(__half2float(__ushort_as_half(
                        (unsigned short)(rk >> 16))));
                }
            }
        }
    }
    for (;;) {                            // async pointer jump (deterministic fixpoint)
        bool ch = false;
        #pragma unroll
        for (int s = 0; s < 4; ++s) {
            const int i = lane + 64 * s;
            if (i < n) {
                const unsigned char p0 = parentS[i];
                const unsigned char np = parentS[p0];
                if (np != p0) { ch = true; parentS[i] = np; }
            }
        }
        if (__ballot(ch) == 0ull) break;
    }
    // ballot-rank renumber; below = lanes strictly below me (well-defined, lane<=63)
    bool isr[4];
    #pragma unroll
    for (int s = 0; s < 4; ++s) {
        const int i = lane + 64 * s;
        isr[s] = (i < n) && (parentS[i] == (unsigned char)i);
    }
    unsigned int base = 0;
    const unsigned long long below = (1ull << lane) - 1ull;
    #pragma unroll
    for (int s = 0; s < 4; ++s) {
        const unsigned long long mask = __ballot(isr[s]);   // uniform execution
        if (isr[s]) {
            const int i = lane + 64 * s;
            newidS[i] = (unsigned char)(base + __popcll(mask & below));
        }
        base += (unsigned int)__popcll(mask);
    }
    if (lane == 0) *ncS = base;
    #pragma unroll
    for (int s = 0; s < 4; ++s) {
        const int i = lane + 64 * s;
        if (i < n) cmapS[i] = newidS[parentS[i]];
    }
}

__global__ void __launch_bounds__(1024) k_all(const float* __restrict__ x,
                                              const float* __restrict__ centres,
                                              const float* __restrict__ sharp,
                                              float* __restrict__ out,
                                              float* __restrict__ m,
                                              unsigned int* __restrict__ rk,
                                              unsigned int* __restrict__ Mp) {
    cg::grid_group grid = cg::this_grid();
    __shared__ __align__(16) char pool[POOL_BYTES];
    __shared__ float sums[25];
    __shared__ unsigned int wred[4];
    __shared__ unsigned int bminS, bmaxS, ncS, dcS;
    __shared__ float deaths[256];
    const int tid = threadIdx.x;
    const int b = blockIdx.x;

    // ================= P1: mean + Mp INF-init =================
    if (tid < 66) Mp[b * 66 + tid] = INF32;   // 256*66 = 16896 = 128*132 exactly
    if (tid < 25) sums[tid] = 0.0f;
    if (tid == 0) { bminS = 0x7F800000u; bmaxS = 0u; dcS = 0u; }
    __syncthreads();
    if (tid < 800) {   // 19200 floats = 800 lanes x 6 float4; 3200 % 25 == 0
        const float* base = x + (long)b * 19200 + 4 * tid;
        float a0 = 0.f, a1 = 0.f, a2 = 0.f, a3 = 0.f;
        #pragma unroll
        for (int i = 0; i < 6; ++i) {
            float4 v = *reinterpret_cast<const float4*>(base + 3200 * i);
            a0 += v.x; a1 += v.y; a2 += v.z; a3 += v.w;
        }
        const int v0 = (4 * tid) % 25;
        atomicAdd(&sums[v0], a0);
        atomicAdd(&sums[(v0 + 1) % 25], a1);
        atomicAdd(&sums[(v0 + 2) % 25], a2);
        atomicAdd(&sums[(v0 + 3) % 25], a3);
    }
    __syncthreads();
    if (tid < 25) m[b * 25 + tid] = sums[tid] * (1.0f / 768.0f);
    grid.sync();

    // ================= P2: feat + D2 row (regs) + row-min key =================
    float* mS    = reinterpret_cast<float*>(pool);
    float* featS = reinterpret_cast<float*>(pool + 25600);
    #pragma unroll
    for (int it = 0; it < 2; ++it) {   // stage m: 1600 float4
        const int o = it * 1024 + tid;
        if (o < 1600) reinterpret_cast<float4*>(mS)[o] =
            reinterpret_cast<const float4*>(m)[o];
    }
    __syncthreads();
    if (tid < 256) {
        float r[25];
        #pragma unroll
        for (int v = 0; v < 25; ++v) r[v] = mS[tid * 25 + v];
        float S1 = 0.f, S2 = 0.f;
        #pragma unroll
        for (int v = 0; v < 25; ++v) { S1 += r[v]; S2 += r[v] * r[v]; }
        float fmn = 1e30f, fmx = -1e30f;
        #pragma unroll
        for (int w = 0; w < 25; ++w) {
            float q = S2 - 2.f * r[w] * S1 + 25.f * r[w] * r[w];
            q = fmaxf(q, 0.f);
            float f = sqrtf(q);
            featS[tid * 25 + w] = f;
            fmn = fminf(fmn, f); fmx = fmaxf(fmx, f);
        }
        if (b == 0) {   // block 0's featS covers all nodes -> global min/max
            atomicMin(&bminS, __float_as_uint(fmn));
            atomicMax(&bmaxS, __float_as_uint(fmx));
        }
    }
    __syncthreads();
    unsigned int w16 = 0;   // D2[b][tid] as fp16 bits — PERSISTS into P3
    if (tid < 256) {
        float fi[25];
        #pragma unroll
        for (int v = 0; v < 25; ++v) fi[v] = featS[b * 25 + v];
        float s = 0.f;
        #pragma unroll
        for (int v = 0; v < 25; ++v) { float d = fi[v] - featS[tid * 25 + v]; s += d * d; }
        w16 = (unsigned int)__half_as_ushort(__float2half(s));
        const unsigned int lo = (b < tid) ? b : tid, hi = (b < tid) ? tid : b;
        unsigned int key = (tid == b) ? INF32 : ((w16 << 16) | (lo << 8) | hi);
        key = dpp_min_step<0x111>(key);
        key = dpp_min_step<0x112>(key);
        key = dpp_min_step<0x114>(key);
        key = dpp_min_step<0x118>(key);
        key = dpp_min_step<0x142>(key);
        key = dpp_min_step<0x143>(key);
        if ((tid & 63) == 63) wred[tid >> 6] = key;
    }
    __syncthreads();
    if (tid == 0) {
        unsigned int b0 = wred[0] < wred[1] ? wred[0] : wred[1];
        unsigned int b1 = wred[2] < wred[3] ? wred[2] : wred[3];
        rk[b] = b0 < b1 ? b0 : b1;
    }
    grid.sync();

    // ================= P3: round-1 hook (replayed) + distributed contraction =====
    unsigned int*  rowKeyS = reinterpret_cast<unsigned int*>(pool);          // 1 KB
    unsigned char* parentS = reinterpret_cast<unsigned char*>(pool + 1024);
    unsigned char* newidS  = reinterpret_cast<unsigned char*>(pool + 1280);
    unsigned char* cmapS   = reinterpret_cast<unsigned char*>(pool + 1536);
    if (tid < 256) rowKeyS[tid] = rk[tid];
    __syncthreads();
    if (tid < 64)
        wave0_phase<false>(256, tid, rowKeyS, parentS, newidS, cmapS,
                           nullptr, &ncS, nullptr);
    __syncthreads();
    if (tid < 256) {
        const unsigned int ca = cmapS[b];
        const unsigned int cb = cmapS[tid];
        if (ca != cb) {
            const unsigned int lo = ca < cb ? ca : cb;
            const unsigned int hi = ca < cb ? cb : ca;
            atomicMin(&Mp[ca * MPSTR + cb], (w16 << 16) | (lo << 8) | hi);
        }
    }
    grid.sync();

    // ================= P4: block 0 — rounds 2+ and structure layer =================
    if (b != 0) return;
    unsigned int* Mb      = reinterpret_cast<unsigned int*>(pool + 4096);    // 85 KB
    float*        outpart = reinterpret_cast<float*>(pool + 89088);          // 4 KB

    // re-hook round 1 (rowKeyS persisted in LDS; records deaths this time)
    if (tid < 64)
        wave0_phase<true>(256, tid, rowKeyS, parentS, newidS, cmapS,
                          deaths, &ncS, &dcS);
    __syncthreads();
    int n = (int)ncS;

    for (int idx = tid; idx < n * SA; idx += 1024) Mb[idx] = Mp[idx];
    __syncthreads();

    int srcOff = 0, srcStr = SA, dstOff = OFF_B, dstStr = SB;
    for (int round = 0; round < 12 && n > 1; ++round) {   // hang guard
        if (tid < n) rowKeyS[tid] = INF32;
        __syncthreads();
        if (tid < 8 * n) {                 // scan: 8 threads per row
            const int a = tid >> 3, sub = tid & 7;
            const unsigned int* row = &Mb[srcOff + a * srcStr];
            unsigned int best = INF32;
            for (int b2 = sub; b2 < n; b2 += 8) {
                const unsigned int v = row[b2];
                best = v < best ? v : best;
            }
            if (best != INF32) atomicMin(&rowKeyS[a], best);
        }
        __syncthreads();
        if (tid < 64)
            wave0_phase<true>(n, tid, rowKeyS, parentS, newidS, cmapS,
                              deaths, &ncS, &dcS);
        __syncthreads();
        const int nc = (int)ncS;
        if (nc > 1) {                      // contract src -> dst
            for (int w = tid; w < nc * dstStr; w += 1024) Mb[dstOff + w] = INF32;
            __syncthreads();
            if (tid < 8 * n) {
                const int a = tid >> 3, sub = tid & 7;
                const unsigned int ca = cmapS[a];
                const unsigned int* row = &Mb[srcOff + a * srcStr];
                for (int b2 = sub; b2 < n; b2 += 8) {
                    const unsigned int cb = cmapS[b2];
                    const unsigned int v = row[b2];
                    if (ca != cb && v != INF32) {
                        const unsigned int lo = ca < cb ? ca : cb;
                        const unsigned int hi = ca < cb ? cb : ca;
                        atomicMin(&Mb[dstOff + ca * dstStr + cb],
                                  (v & 0xFFFF0000u) | (lo << 8) | hi);
                    }
                }
            }
            __syncthreads();
        }
        const int t1 = srcOff; srcOff = dstOff; dstOff = t1;
        const int t2 = srcStr; srcStr = dstStr; dstStr = t2;
        n = nc;
    }

    // structure-element layer: out[k] = sum_i exp(-c0^2 s0^2 - (d_i-c1)^2 s1^2)
    const float mn = __uint_as_float(bminS);
    const float mx = __uint_as_float(bmaxS);
    const float inv = 1.0f / (mx - mn);
    const int k = tid & 63;
    const int part = tid >> 6;
    const float c0 = centres[2 * k], c1 = centres[2 * k + 1];
    const float s0 = sharp[2 * k],   s1 = sharp[2 * k + 1];
    const float t0 = c0 * c0 * s0 * s0;
    const float s1sq = s1 * s1;
    float acc = 0.f;
    for (int idx = part; idx < 255; idx += 16) {
        const float d = deaths[idx] * inv - c1;
        acc += __expf(-(t0 + d * d * s1sq));
    }
    outpart[tid] = acc;
    __syncthreads();
    if (tid < 64) {
        float s = 0.f;
        #pragma unroll
        for (int pp = 0; pp < 16; ++pp) s += outpart[tid + 64 * pp];
        out[tid] = s;
    }
}

extern "C" void kernel_launch(void* const* d_in, const int* in_sizes, int n_in,
                              void* d_out, int out_size, void* d_ws, size_t ws_size,
                              hipStream_t stream) {
    const float* x       = (const float*)d_in[0];
    const float* centres = (const float*)d_in[1];
    const float* sharp   = (const float*)d_in[2];
    float* out = (float*)d_out;
    char* ws = (char*)d_ws;
    float*        m  = (float*)(ws + WS_M);
    unsigned int* rk = (unsigned int*)(ws + WS_RK);
    unsigned int* Mp = (unsigned int*)(ws + WS_MP);

    void* args[] = { (void*)&x, (void*)&centres, (void*)&sharp,
                     (void*)&out, (void*)&m, (void*)&rk, (void*)&Mp };
    hipLaunchCooperativeKernel((const void*)k_all, dim3(256), dim3(1024),
                               args, 0, stream);
}

// Round 8
// 92.606 us; speedup vs baseline: 1.7931x; 1.7931x over previous
//
#include <hip/hip_runtime.h>
#include <hip/hip_fp16.h>

// Problem: Topo_60653528154131
//   x:[256,3,256,25] f32, centres:[64,2] f32, sharpness:[64,2] f32 -> out:[64] f32
//
// Pipeline (4 kernels — separate graph nodes are the cheap grid barrier; measured
// cooperative grid.sync() = ~26 us/barrier on this 8-XCD part, R7):
//   K1 k_mean     : m[n,v] = mean_{c,t} x  (HBM-bound) + INF-init of Mp region
//   K2 k_dist     : feat (redundant per block), D2 row -> D16, row-min key -> rowKeyG,
//                   block 0 -> feat min/max
//   K3 k_contract : 256 blocks. Each block deterministically replays Boruvka round-1
//                   hooking from rowKeyG (ballot-rank renumber -> identical cmap in
//                   every block), folds ITS row of D16 into Mp[ca][cb] via GLOBAL
//                   atomicMin (distributed over 256 CUs). Block 0 additionally
//                   records round-1 deaths + comp count to global.
//   K4 k_mst      : 1 block. Load deaths/n from global, load Mp (n<=128) to LDS,
//                   Boruvka rounds 2+ on shrinking matrices,
//                   deaths = sqrt(D2)/(max-min), structure-element layer.
//
// ws layout:
//   m       [6400]  f32 @ 0
//   mm      [2]     u32 @ 25600
//   rowKeyG [256]   u32 @ 28672
//   deathsG [256]   f32 @ 29696
//   ncdcG   [2]     u32 @ 30720   (n after round 1, deaths count after round 1)
//   D16     [65536] u16 @ 65536   (fp16 bits of D^2)
//   Mp      [128*132] u32 @ 196608 (round-1 contracted matrix, stride 132)

#define WS_M    0
#define WS_MM   25600
#define WS_RK   28672
#define WS_DTH  29696
#define WS_NCDC 30720
#define WS_D16  65536
#define WS_MP   196608

#define INF32 0xFFFFFFFFu
#define MPSTR 132

// ---------------- K1: channel+time mean + Mp INF-init ----------------
__global__ void k_mean(const float* __restrict__ x, float* __restrict__ m,
                       unsigned int* __restrict__ Mp) {
    const int n = blockIdx.x;
    const int tid = threadIdx.x;
    if (tid < 66) Mp[n * 66 + tid] = INF32;   // 256*66 = 16896 = 128*132 exactly
    __shared__ float sums[25];
    if (tid < 25) sums[tid] = 0.0f;
    __syncthreads();
    if (tid < 200) {
        const float* base = x + (long)n * 19200 + 4 * tid;
        float a0 = 0.f, a1 = 0.f, a2 = 0.f, a3 = 0.f;
        #pragma unroll
        for (int i = 0; i < 24; ++i) {
            float4 v = *reinterpret_cast<const float4*>(base + 800 * i);
            a0 += v.x; a1 += v.y; a2 += v.z; a3 += v.w;
        }
        const int v0 = (4 * tid) % 25;
        atomicAdd(&sums[v0], a0);
        atomicAdd(&sums[(v0 + 1) % 25], a1);
        atomicAdd(&sums[(v0 + 2) % 25], a2);
        atomicAdd(&sums[(v0 + 3) % 25], a3);
    }
    __syncthreads();
    if (tid < 25) m[n * 25 + tid] = sums[tid] * (1.0f / 768.0f);
}

// wave64 min-reduce step via DPP: invalid lanes keep old=INF
template <int CTRL>
__device__ __forceinline__ unsigned int dpp_min_step(unsigned int v) {
    unsigned int t = (unsigned int)__builtin_amdgcn_update_dpp(
        (int)0xFFFFFFFF, (int)v, CTRL, 0xF, 0xF, false);
    return (t < v) ? t : v;
}

// ---------------- K2: feat + D2 row + row-min key + minmax ----------------
__global__ void __launch_bounds__(256) k_dist(const float* __restrict__ m,
                                              unsigned short* __restrict__ D16,
                                              unsigned int* __restrict__ rowKeyG,
                                              unsigned int* __restrict__ mm) {
    __shared__ float mS[6400];
    __shared__ float featS[6400];
    __shared__ unsigned int bmin, bmax;
    __shared__ unsigned int wred[4];
    const int i = blockIdx.x;
    const int t = threadIdx.x;
    if (t == 0) { bmin = 0x7F800000u; bmax = 0u; }
    #pragma unroll
    for (int it = 0; it < 7; ++it) {
        int o = it * 256 + t;
        if (o < 1600) reinterpret_cast<float4*>(mS)[o] =
            reinterpret_cast<const float4*>(m)[o];
    }
    __syncthreads();
    float r[25];
    #pragma unroll
    for (int v = 0; v < 25; ++v) r[v] = mS[t * 25 + v];
    float S1 = 0.f, S2 = 0.f;
    #pragma unroll
    for (int v = 0; v < 25; ++v) { S1 += r[v]; S2 += r[v] * r[v]; }
    float fmn = 1e30f, fmx = -1e30f;
    #pragma unroll
    for (int w = 0; w < 25; ++w) {
        float q = S2 - 2.f * r[w] * S1 + 25.f * r[w] * r[w];
        q = fmaxf(q, 0.f);
        float f = sqrtf(q);
        featS[t * 25 + w] = f;
        fmn = fminf(fmn, f); fmx = fmaxf(fmx, f);
    }
    if (i == 0) {
        atomicMin(&bmin, __float_as_uint(fmn));
        atomicMax(&bmax, __float_as_uint(fmx));
    }
    __syncthreads();
    if (i == 0 && t == 0) { mm[0] = bmin; mm[1] = bmax; }
    float fi[25];
    #pragma unroll
    for (int v = 0; v < 25; ++v) fi[v] = featS[i * 25 + v];
    float s = 0.f;
    #pragma unroll
    for (int v = 0; v < 25; ++v) { float d = fi[v] - featS[t * 25 + v]; s += d * d; }
    const unsigned int w16 = (unsigned int)__half_as_ushort(__float2half(s));
    D16[i * 256 + t] = (unsigned short)w16;
    const unsigned int lo = (i < t) ? i : t, hi = (i < t) ? t : i;
    unsigned int key = (t == i) ? INF32 : ((w16 << 16) | (lo << 8) | hi);
    key = dpp_min_step<0x111>(key);
    key = dpp_min_step<0x112>(key);
    key = dpp_min_step<0x114>(key);
    key = dpp_min_step<0x118>(key);
    key = dpp_min_step<0x142>(key);
    key = dpp_min_step<0x143>(key);
    if ((t & 63) == 63) wred[t >> 6] = key;
    __syncthreads();
    if (t == 0) {
        unsigned int b0 = wred[0] < wred[1] ? wred[0] : wred[1];
        unsigned int b1 = wred[2] < wred[3] ? wred[2] : wred[3];
        rowKeyG[i] = b0 < b1 ? b0 : b1;
    }
}

// ---------------- wave0 Boruvka phase (DETERMINISTIC) ----------------
// hook -> 2-cycle break (optional death record) -> async pointer jump ->
// ballot-rank renumber (deterministic: identical cmap/nc in every block).
// Wave-0 lanes only; no __syncthreads inside.
template <bool RECORD>
__device__ __forceinline__ void wave0_phase(int n, int lane,
        unsigned int* rowKeyS, unsigned char* parentS, unsigned char* newidS,
        unsigned char* cmapS, float* deaths, unsigned int* ncS, unsigned int* dcS) {
    unsigned int par[4];
    #pragma unroll
    for (int s = 0; s < 4; ++s) {         // hook
        const int i = lane + 64 * s;
        if (i < n) {
            const unsigned int rk = rowKeyS[i];
            const unsigned int u = (rk >> 8) & 0xFFu, v = rk & 0xFFu;
            unsigned int p = (u == (unsigned int)i) ? v : u;
            if (rk == INF32) p = (unsigned int)i;  // safety; complete graph: unused
            par[s] = p;
            parentS[i] = (unsigned char)p;
        }
    }
    #pragma unroll
    for (int s = 0; s < 4; ++s) {         // break mutual 2-cycles
        const int i = lane + 64 * s;
        if (i < n) {
            const unsigned int p = par[s];
            if (p != (unsigned int)i) {
                if (parentS[p] == (unsigned char)i && (unsigned int)i < p) {
                    parentS[i] = (unsigned char)i;   // winner stays root, no death
                } else if (RECORD) {
                    const unsigned int d = atomicAdd(dcS, 1u);
                    const unsigned int rk = rowKeyS[i];
                    deaths[d] = sqrtf(__half2float(__ushort_as_half(
                        (unsigned short)(rk >> 16))));
                }
            }
        }
    }
    for (;;) {                            // async pointer jump (deterministic fixpoint)
        bool ch = false;
        #pragma unroll
        for (int s = 0; s < 4; ++s) {
            const int i = lane + 64 * s;
            if (i < n) {
                const unsigned char p0 = parentS[i];
                const unsigned char np = parentS[p0];
                if (np != p0) { ch = true; parentS[i] = np; }
            }
        }
        if (__ballot(ch) == 0ull) break;
    }
    // ballot-rank renumber; below = lanes strictly below me (well-defined, lane<=63)
    bool isr[4];
    #pragma unroll
    for (int s = 0; s < 4; ++s) {
        const int i = lane + 64 * s;
        isr[s] = (i < n) && (parentS[i] == (unsigned char)i);
    }
    unsigned int base = 0;
    const unsigned long long below = (1ull << lane) - 1ull;
    #pragma unroll
    for (int s = 0; s < 4; ++s) {
        const unsigned long long mask = __ballot(isr[s]);   // uniform execution
        if (isr[s]) {
            const int i = lane + 64 * s;
            newidS[i] = (unsigned char)(base + __popcll(mask & below));
        }
        base += (unsigned int)__popcll(mask);
    }
    if (lane == 0) *ncS = base;
    #pragma unroll
    for (int s = 0; s < 4; ++s) {
        const int i = lane + 64 * s;
        if (i < n) cmapS[i] = newidS[parentS[i]];
    }
}

// ---------------- K3: distributed round-1 contraction (+ deaths from block 0) ----
__global__ void __launch_bounds__(256) k_contract(const unsigned short* __restrict__ D16g,
                                                  const unsigned int* __restrict__ rowKeyG,
                                                  unsigned int* __restrict__ Mp,
                                                  float* __restrict__ deathsG,
                                                  unsigned int* __restrict__ ncdcG) {
    __shared__ unsigned int rowKeyS[256];
    __shared__ unsigned char parentS[256], newidS[256], cmapS[256];
    __shared__ unsigned int ncS, dcS;
    __shared__ float deathsS[256];
    const int tid = threadIdx.x;
    const int b = blockIdx.x;
    rowKeyS[tid] = rowKeyG[tid];
    if (tid == 0) dcS = 0;
    __syncthreads();
    if (tid < 64) {
        if (b == 0)
            wave0_phase<true>(256, tid, rowKeyS, parentS, newidS, cmapS,
                              deathsS, &ncS, &dcS);
        else
            wave0_phase<false>(256, tid, rowKeyS, parentS, newidS, cmapS,
                               nullptr, &ncS, nullptr);
    }
    __syncthreads();
    if (b == 0) {   // publish round-1 deaths + counts (deterministic multiset)
        if (tid < dcS) deathsG[tid] = deathsS[tid];
        if (tid == 0) { ncdcG[0] = ncS; ncdcG[1] = dcS; }
    }
    // fold row b into Mp via global atomicMin (distributed across 256 CUs)
    const unsigned int ca = cmapS[b];
    const unsigned int cb = cmapS[tid];
    if (ca != cb) {
        const unsigned int w16 = (unsigned int)D16g[b * 256 + tid];
        const unsigned int lo = ca < cb ? ca : cb;
        const unsigned int hi = ca < cb ? cb : ca;
        atomicMin(&Mp[ca * MPSTR + cb], (w16 << 16) | (lo << 8) | hi);
    }
}

// ---------------- K4: Boruvka rounds 2+ on contracted matrix + structure layer ----
#define SA 132   // u32 stride, buffer A (cap 128 rows)
#define SB 68    // u32 stride, buffer B (cap 64 rows)
#define OFF_B (128 * SA)

__global__ void __launch_bounds__(1024) k_mst(const unsigned int* __restrict__ Mp,
                                              const float* __restrict__ deathsG,
                                              const unsigned int* __restrict__ ncdcG,
                                              const unsigned int* __restrict__ mm,
                                              const float* __restrict__ centres,
                                              const float* __restrict__ sharp,
                                              float* __restrict__ out) {
    __shared__ unsigned int Mb[128 * SA + 64 * SB];   // 85 KB ping-pong
    __shared__ unsigned int rowKeyS[256];
    __shared__ unsigned char parentS[256], newidS[256], cmapS[256];
    __shared__ unsigned int ncS, dcS;
    __shared__ float deaths[256];
    __shared__ float outpart[1024];
    const int tid = threadIdx.x;

    // round-1 results from k_contract: n, deaths so far
    if (tid == 0) { ncS = ncdcG[0]; dcS = ncdcG[1]; }
    if (tid < 256) deaths[tid] = deathsG[tid];   // only [0,dcS) meaningful
    __syncthreads();
    int n = (int)ncS;

    // load contracted matrix Mp (n x n, stride MPSTR==SA) into buffer A
    for (int idx = tid; idx < n * SA; idx += 1024) Mb[idx] = Mp[idx];
    __syncthreads();

    // rounds 2+ (bounded: Boruvka on <=256 nodes needs <=8 rounds; 12 = hang guard)
    int srcOff = 0, srcStr = SA, dstOff = OFF_B, dstStr = SB;
    for (int round = 0; round < 12 && n > 1; ++round) {
        if (tid < n) rowKeyS[tid] = INF32;
        __syncthreads();
        if (tid < 8 * n) {                 // scan: 8 threads per row
            const int a = tid >> 3, sub = tid & 7;
            const unsigned int* row = &Mb[srcOff + a * srcStr];
            unsigned int best = INF32;
            for (int b2 = sub; b2 < n; b2 += 8) {
                const unsigned int v = row[b2];
                best = v < best ? v : best;
            }
            if (best != INF32) atomicMin(&rowKeyS[a], best);
        }
        __syncthreads();
        if (tid < 64)
            wave0_phase<true>(n, tid, rowKeyS, parentS, newidS, cmapS,
                              deaths, &ncS, &dcS);
        __syncthreads();
        const int nc = (int)ncS;
        if (nc > 1) {                      // contract src -> dst
            for (int w = tid; w < nc * dstStr; w += 1024) Mb[dstOff + w] = INF32;
            __syncthreads();
            if (tid < 8 * n) {
                const int a = tid >> 3, sub = tid & 7;
                const unsigned int ca = cmapS[a];
                const unsigned int* row = &Mb[srcOff + a * srcStr];
                for (int b2 = sub; b2 < n; b2 += 8) {
                    const unsigned int cb = cmapS[b2];
                    const unsigned int v = row[b2];
                    if (ca != cb && v != INF32) {
                        const unsigned int lo = ca < cb ? ca : cb;
                        const unsigned int hi = ca < cb ? cb : ca;
                        atomicMin(&Mb[dstOff + ca * dstStr + cb],
                                  (v & 0xFFFF0000u) | (lo << 8) | hi);
                    }
                }
            }
            __syncthreads();
        }
        const int t1 = srcOff; srcOff = dstOff; dstOff = t1;
        const int t2 = srcStr; srcStr = dstStr; dstStr = t2;
        n = nc;
    }

    // structure-element layer: out[k] = sum_i exp(-c0^2 s0^2 - (d_i-c1)^2 s1^2)
    const float mn = __uint_as_float(mm[0]);
    const float mx = __uint_as_float(mm[1]);
    const float inv = 1.0f / (mx - mn);
    const int k = tid & 63;
    const int part = tid >> 6;
    const float c0 = centres[2 * k], c1 = centres[2 * k + 1];
    const float s0 = sharp[2 * k],   s1 = sharp[2 * k + 1];
    const float t0 = c0 * c0 * s0 * s0;
    const float s1sq = s1 * s1;
    float acc = 0.f;
    for (int idx = part; idx < 255; idx += 16) {
        const float d = deaths[idx] * inv - c1;
        acc += __expf(-(t0 + d * d * s1sq));
    }
    outpart[tid] = acc;
    __syncthreads();
    if (tid < 64) {
        float s = 0.f;
        #pragma unroll
        for (int pp = 0; pp < 16; ++pp) s += outpart[tid + 64 * pp];
        out[tid] = s;
    }
}

extern "C" void kernel_launch(void* const* d_in, const int* in_sizes, int n_in,
                              void* d_out, int out_size, void* d_ws, size_t ws_size,
                              hipStream_t stream) {
    const float* x       = (const float*)d_in[0];
    const float* centres = (const float*)d_in[1];
    const float* sharp   = (const float*)d_in[2];
    float* out = (float*)d_out;
    char* ws = (char*)d_ws;
    float*          m    = (float*)(ws + WS_M);
    unsigned int*   mm   = (unsigned int*)(ws + WS_MM);
    unsigned int*   rk   = (unsigned int*)(ws + WS_RK);
    float*          dth  = (float*)(ws + WS_DTH);
    unsigned int*   ncdc = (unsigned int*)(ws + WS_NCDC);
    unsigned short* D16  = (unsigned short*)(ws + WS_D16);
    unsigned int*   Mp   = (unsigned int*)(ws + WS_MP);

    k_mean<<<256, 256, 0, stream>>>(x, m, Mp);
    k_dist<<<256, 256, 0, stream>>>(m, D16, rk, mm);
    k_contract<<<256, 256, 0, stream>>>(D16, rk, Mp, dth, ncdc);
    k_mst<<<1, 1024, 0, stream>>>(Mp, dth, ncdc, mm, centres, sharp, out);
}